// Round 3
// baseline (642.980 us; speedup 1.0000x reference)
//
#include <hip/hip_runtime.h>

// MaxPoolAggregator: out[q, :] = max over s of features[nbrs[q,s], :]
// features: float32 [N_NODES, 128]   (512 B per row)
// nbrs:     int32   [N_QUERY, S]
// out:      float32 [N_QUERY, 128]
//
// Round-3 design: ONE WAVE PER QUERY.
//  - The 10 neighbor indices are wave-uniform -> compiler emits scalar
//    s_load (SMEM) instead of 10 redundant per-lane VMEM loads.
//  - Each lane owns 8 B (float2) of the 512 B row: one gather instruction
//    reads one full row as a single contiguous 512 B segment, addressed as
//    SGPR row base + small VGPR lane offset (no per-lane 64-bit VALU math).
//  - 10 unrolled gathers -> 5 KB outstanding per wave for latency hiding.
//  - Non-temporal output stores keep L3 capacity for feature-row reuse.

typedef __attribute__((ext_vector_type(2))) float f32x2;

template <int S>
__global__ __launch_bounds__(256) void maxpool_wave(
    const float* __restrict__ feats,
    const int* __restrict__ nbrs,
    float* __restrict__ out,
    int n_query)
{
    const int wave = blockIdx.x * (blockDim.x >> 6) + (threadIdx.x >> 6);
    const int lane = threadIdx.x & 63;
    if (wave >= n_query) return;

    // wave-uniform query id (readfirstlane makes uniformity explicit)
    const int q = __builtin_amdgcn_readfirstlane(wave);

    // wave-uniform neighbor indices -> scalar loads
    const int* np = nbrs + (size_t)q * S;
    int idxs[S];
    #pragma unroll
    for (int s = 0; s < S; ++s)
        idxs[s] = __builtin_amdgcn_readfirstlane(np[s]);

    // lane's float2 column within a row
    const f32x2* fcol = (const f32x2*)feats + lane;   // row stride = 64 f32x2

    f32x2 m = fcol[(size_t)idxs[0] * 64];
    #pragma unroll
    for (int s = 1; s < S; ++s) {
        f32x2 v = fcol[(size_t)idxs[s] * 64];
        m.x = fmaxf(m.x, v.x);
        m.y = fmaxf(m.y, v.y);
    }

    f32x2* op = (f32x2*)out + (size_t)q * 64 + lane;
    __builtin_nontemporal_store(m, op);
}

__global__ __launch_bounds__(256) void maxpool_generic(
    const float* __restrict__ feats,
    const int* __restrict__ nbrs,
    float* __restrict__ out,
    int n_query, int num_sample)
{
    const int wave = blockIdx.x * (blockDim.x >> 6) + (threadIdx.x >> 6);
    const int lane = threadIdx.x & 63;
    if (wave >= n_query) return;

    const int q = __builtin_amdgcn_readfirstlane(wave);
    const int* np = nbrs + (size_t)q * num_sample;
    const f32x2* fcol = (const f32x2*)feats + lane;

    f32x2 m = fcol[(size_t)__builtin_amdgcn_readfirstlane(np[0]) * 64];
    for (int s = 1; s < num_sample; ++s) {
        int nbr = __builtin_amdgcn_readfirstlane(np[s]);
        f32x2 v = fcol[(size_t)nbr * 64];
        m.x = fmaxf(m.x, v.x);
        m.y = fmaxf(m.y, v.y);
    }
    f32x2* op = (f32x2*)out + (size_t)q * 64 + lane;
    __builtin_nontemporal_store(m, op);
}

extern "C" void kernel_launch(void* const* d_in, const int* in_sizes, int n_in,
                              void* d_out, int out_size, void* d_ws, size_t ws_size,
                              hipStream_t stream) {
    const float* feats = (const float*)d_in[0];
    const int*   nbrs  = (const int*)d_in[1];
    float*       out   = (float*)d_out;

    const int D = 128;
    int n_query = out_size / D;
    int num_sample = (n_query > 0) ? (in_sizes[1] / n_query) : 1;

    const int waves_per_block = 4;               // 256 threads
    int blocks = (n_query + waves_per_block - 1) / waves_per_block;

    if (num_sample == 10) {
        maxpool_wave<10><<<blocks, 256, 0, stream>>>(feats, nbrs, out, n_query);
    } else {
        maxpool_generic<<<blocks, 256, 0, stream>>>(feats, nbrs, out, n_query, num_sample);
    }
}